// Round 11
// baseline (931.685 us; speedup 1.0000x reference)
//
#include <hip/hip_runtime.h>
#include <cstdint>
#include <cstddef>

#define NN 50000
#define NE 800000
#define FIN 128
#define HID 256
#define NCLS 10
#define NG 64
#define LDT 1280        // Tbig row stride in elements (5 * 256)

// counting-sort geometry: key = dst*NCH + (src>>12); chunk = 4096 src rows
#define NCH 13
#define NCELL (NN * NCH)              // 650,000 (even)
#define NSCB ((NCELL + 255) / 256)    // 2540 scan blocks
#define NDISB ((NN + 255) / 256)      // 196 blocks for dis

// fused preproc kernel block ranges
#define FB 3125                        // fill blocks
#define WTB 2688                       // wtall blocks (384+1024+1280)
#define SXB 12500                      // spread_x blocks

typedef unsigned int uint;
typedef unsigned short ushort;
typedef __attribute__((ext_vector_type(8))) short short8;
typedef __attribute__((ext_vector_type(4))) float f32x4;

static inline size_t align_up(size_t v, size_t a) { return (v + a - 1) / a * a; }

__device__ __forceinline__ float bf2f(ushort u) {
    union { uint i; float f; } v; v.i = (uint)u << 16; return v.f;
}
__device__ __forceinline__ ushort f2bf(float f) {
    union { uint i; float f; } v; v.f = f;
    uint i = v.i;
    uint r = (i + 0x7fffu + ((i >> 16) & 1u)) >> 16;
    return (ushort)r;
}
__device__ __forceinline__ uint pack2(float a, float b) {
    return (uint)f2bf(a) | ((uint)f2bf(b) << 16);
}

// ---------------- graph preprocessing ----------------
// cellcnt packed 2 cells/u32; atomic old value = edge's rank within cell.

__global__ void k_degcnt(const int* __restrict__ src, const int* __restrict__ dst,
                         int* __restrict__ ideg, uint* __restrict__ cellcnt32,
                         ushort* __restrict__ rank16) {
    int e = blockIdx.x * 256 + threadIdx.x;
    if (e < NE) {
        int s = src[e], d = dst[e];
        atomicAdd(&ideg[s], 1);
        int cell = d * NCH + (s >> 12);
        uint old = atomicAdd(&cellcnt32[cell >> 1], 1u << ((cell & 1) * 16));
        rank16[e] = (ushort)((old >> ((cell & 1) * 16)) & 0xffffu);
    }
}

// scanA over NCELL packed counts; extra blocks compute dis from ideg
__global__ void k_scanA_dis(const uint* __restrict__ cnt32, int* __restrict__ rp,
                            int* __restrict__ bsum, const int* __restrict__ ideg,
                            float* __restrict__ dis) {
    if (blockIdx.x >= NSCB) {
        int n = (blockIdx.x - NSCB) * 256 + threadIdx.x;
        if (n < NN) {
            int d = ideg[n];
            dis[n] = (d > 0) ? rsqrtf((float)d) : 0.0f;
        }
        return;
    }
    __shared__ int s[256];
    int i = blockIdx.x * 256 + threadIdx.x;
    int v = 0;
    if (i < NCELL) v = (int)((cnt32[i >> 1] >> ((i & 1) * 16)) & 0xffffu);
    s[threadIdx.x] = v;
    __syncthreads();
    for (int off = 1; off < 256; off <<= 1) {
        int t = (threadIdx.x >= (unsigned)off) ? s[threadIdx.x - off] : 0;
        __syncthreads();
        s[threadIdx.x] += t;
        __syncthreads();
    }
    if (i < NCELL) rp[i] = s[threadIdx.x] - v;
    if (threadIdx.x == 255) bsum[blockIdx.x] = s[255];
}

// in-place exclusive scan, single block of 1024, multi-pass
__global__ void k_scanB(int* __restrict__ b, int n) {
    __shared__ int s[1024];
    __shared__ int carry;
    if (threadIdx.x == 0) carry = 0;
    __syncthreads();
    for (int base = 0; base < n; base += 1024) {
        int i = base + threadIdx.x;
        int v = (i < n) ? b[i] : 0;
        s[threadIdx.x] = v;
        __syncthreads();
        for (int off = 1; off < 1024; off <<= 1) {
            int t = (threadIdx.x >= (unsigned)off) ? s[threadIdx.x - off] : 0;
            __syncthreads();
            s[threadIdx.x] += t;
            __syncthreads();
        }
        int c = carry;
        if (i < n) b[i] = c + s[threadIdx.x] - v;
        __syncthreads();
        if (threadIdx.x == 0) carry = c + s[1023];
        __syncthreads();
    }
}

__global__ void k_scanC(const int* __restrict__ bsum, int* __restrict__ rp,
                        int* __restrict__ rpn) {
    int i = blockIdx.x * 256 + threadIdx.x;
    if (i < NCELL) {
        int v = rp[i] + bsum[blockIdx.x];
        rp[i] = v;
        if (i % NCH == 0) rpn[i / NCH] = v;   // node-level row ptr
    }
    if (i == 0) rpn[NN] = NE;
}

// ---------------- fused: fill (atomic-free) + weight transpose + spread_x ---
__global__ void k_fused_prep(
    const int* __restrict__ src, const int* __restrict__ dst,
    const float* __restrict__ dis, const int* __restrict__ cellptr,
    const ushort* __restrict__ rank16, uint2* __restrict__ em,
    const float* __restrict__ W1, const float* __restrict__ W2,
    const float* __restrict__ W3, ushort* __restrict__ Wt1,
    ushort* __restrict__ Wt2, ushort* __restrict__ Wt3,
    const float* __restrict__ x, ushort* __restrict__ T) {
    int b = blockIdx.x;
    if (b < FB) {
        int e = b * 256 + threadIdx.x;
        if (e < NE) {
            int s = src[e], d = dst[e];
            int cell = d * NCH + (s >> 12);
            int pos = cellptr[cell] + (int)rank16[e];
            uint2 m;
            m.x = (uint)s;
            m.y = __float_as_uint(-dis[s] * dis[d]);
            em[pos] = m;
        }
        return;
    }
    if (b < FB + WTB) {
        int i = (b - FB) * 256 + threadIdx.x;
        if (i < 384 * 256) {
            int k = i >> 8, n = i & 255;
            Wt1[(size_t)n * 384 + k] = f2bf(W1[i]);
            return;
        }
        i -= 384 * 256;
        if (i < 1024 * 256) {
            int k = i >> 8, n = i & 255;
            Wt2[(size_t)n * 1024 + k] = f2bf(W2[i]);
            return;
        }
        i -= 1024 * 256;
        if (i < 1280 * 256) {
            int k = i >> 8, n = i & 255;
            Wt3[(size_t)n * 1280 + k] = f2bf(W3[i]);
        }
        return;
    }
    int i = (b - FB - WTB) * 256 + threadIdx.x;
    if (i < NN * 64) {
        int m = i >> 6, p = i & 63;
        const float* xp = x + (size_t)m * FIN + p * 2;
        uint* tp = (uint*)(T + (size_t)m * LDT) + p;
        *tp = pack2(xp[0], xp[1]);
    }
}

// ---------------- prop F=128: wave-per-node, 8-deep (r8 form) ----------------
template <int FUSE>
__global__ __launch_bounds__(512) void k_prop128(
    const int* __restrict__ rpn, const uint2* __restrict__ em,
    const ushort* __restrict__ h, const ushort* __restrict__ sub,
    ushort* __restrict__ out) {
    int wv = __builtin_amdgcn_readfirstlane(threadIdx.x >> 6);
    int d = blockIdx.x * 8 + wv;
    int lane = threadIdx.x & 63;
    int beg = rpn[d], end = rpn[d + 1];
    float a0 = 0.0f, a1 = 0.0f;

    int e = beg;
    int nfull = (end - beg) >> 3;
    if (nfull > 0) {
        uint2 mt[8];
#pragma unroll
        for (int u = 0; u < 8; ++u) mt[u] = em[e + u];
        for (int g = 0; g < nfull; ++g) {
            uint2 mtn[8];
            uint gg[8];
#pragma unroll
            for (int u = 0; u < 8; ++u)
                gg[u] = *((const uint*)(h + (size_t)mt[u].x * LDT) + lane);
#pragma unroll
            for (int u = 0; u < 8; ++u) {
                int pe = e + 8 + u; if (pe > end - 1) pe = end - 1;
                mtn[u] = em[pe];
            }
#pragma unroll
            for (int u = 0; u < 8; ++u) {
                float wvv = __uint_as_float(mt[u].y);
                a0 += wvv * bf2f((ushort)gg[u]);
                a1 += wvv * bf2f((ushort)(gg[u] >> 16));
            }
#pragma unroll
            for (int u = 0; u < 8; ++u) mt[u] = mtn[u];
            e += 8;
        }
    }
    for (; e < end; ++e) {
        uint2 m0 = em[e];
        float w0 = __uint_as_float(m0.y);
        uint g0 = *((const uint*)(h + (size_t)m0.x * LDT) + lane);
        a0 += w0 * bf2f((ushort)g0);
        a1 += w0 * bf2f((ushort)(g0 >> 16));
    }

    uint* op = (uint*)(out + (size_t)d * LDT) + lane;
    if (FUSE) {
        uint sv = *((const uint*)(sub + (size_t)d * LDT) + lane);
        *op = pack2(2.0f * a0 - bf2f((ushort)sv),
                    2.0f * a1 - bf2f((ushort)(sv >> 16)));
    } else {
        *op = pack2(a0, a1);
    }
}

// ---------------- prop F=256: uint4 gathers, 2 edges per instruction --------
// 32 lanes cover a 512B row; lane-half picks even/odd edge of each pair.
// Cross-half combine via shfl_xor(32) at the end; lanes 0-31 write 16B.
template <int FUSE>
__global__ __launch_bounds__(512) void k_prop256(
    const int* __restrict__ rpn, const uint2* __restrict__ em,
    const ushort* __restrict__ h, const ushort* __restrict__ sub,
    ushort* __restrict__ out) {
    int wv = __builtin_amdgcn_readfirstlane(threadIdx.x >> 6);
    int d = blockIdx.x * 8 + wv;
    int lane = threadIdx.x & 63;
    int half = lane >> 5;
    int l32 = lane & 31;
    int beg = rpn[d], end = rpn[d + 1];
    float acc[8];
#pragma unroll
    for (int j = 0; j < 8; ++j) acc[j] = 0.0f;

    int e = beg;
    int nb = (end - beg) >> 3;   // batches of 8 edges (4 gathers)
    if (nb > 0) {
        uint2 mt[8];
#pragma unroll
        for (int u = 0; u < 8; ++u) mt[u] = em[e + u];
        for (int g = 0; g < nb; ++g) {
            uint2 mtn[8];
            uint4 gv[4];
#pragma unroll
            for (int u = 0; u < 4; ++u) {
                uint2 m = half ? mt[2 * u + 1] : mt[2 * u];
                gv[u] = *((const uint4*)(h + (size_t)m.x * LDT) + l32);
            }
#pragma unroll
            for (int u = 0; u < 8; ++u) {
                int pe = e + 8 + u; if (pe > end - 1) pe = end - 1;
                mtn[u] = em[pe];
            }
#pragma unroll
            for (int u = 0; u < 4; ++u) {
                uint2 m = half ? mt[2 * u + 1] : mt[2 * u];
                float w = __uint_as_float(m.y);
                acc[0] += w * bf2f((ushort)gv[u].x);
                acc[1] += w * bf2f((ushort)(gv[u].x >> 16));
                acc[2] += w * bf2f((ushort)gv[u].y);
                acc[3] += w * bf2f((ushort)(gv[u].y >> 16));
                acc[4] += w * bf2f((ushort)gv[u].z);
                acc[5] += w * bf2f((ushort)(gv[u].z >> 16));
                acc[6] += w * bf2f((ushort)gv[u].w);
                acc[7] += w * bf2f((ushort)(gv[u].w >> 16));
            }
#pragma unroll
            for (int u = 0; u < 8; ++u) mt[u] = mtn[u];
            e += 8;
        }
    }
    for (; e + 2 <= end; e += 2) {
        uint2 m = half ? em[e + 1] : em[e];
        uint4 gvv = *((const uint4*)(h + (size_t)m.x * LDT) + l32);
        float w = __uint_as_float(m.y);
        acc[0] += w * bf2f((ushort)gvv.x); acc[1] += w * bf2f((ushort)(gvv.x >> 16));
        acc[2] += w * bf2f((ushort)gvv.y); acc[3] += w * bf2f((ushort)(gvv.y >> 16));
        acc[4] += w * bf2f((ushort)gvv.z); acc[5] += w * bf2f((ushort)(gvv.z >> 16));
        acc[6] += w * bf2f((ushort)gvv.w); acc[7] += w * bf2f((ushort)(gvv.w >> 16));
    }
    if (e < end) {  // single leftover: half==1 contributes 0
        uint2 m = em[e];
        uint4 gvv = *((const uint4*)(h + (size_t)m.x * LDT) + l32);
        float w = half ? 0.0f : __uint_as_float(m.y);
        acc[0] += w * bf2f((ushort)gvv.x); acc[1] += w * bf2f((ushort)(gvv.x >> 16));
        acc[2] += w * bf2f((ushort)gvv.y); acc[3] += w * bf2f((ushort)(gvv.y >> 16));
        acc[4] += w * bf2f((ushort)gvv.z); acc[5] += w * bf2f((ushort)(gvv.z >> 16));
        acc[6] += w * bf2f((ushort)gvv.w); acc[7] += w * bf2f((ushort)(gvv.w >> 16));
    }
    // combine even-edge and odd-edge partials across lane halves
#pragma unroll
    for (int j = 0; j < 8; ++j) acc[j] += __shfl_xor(acc[j], 32);

    if (half == 0) {
        uint4* op = (uint4*)(out + (size_t)d * LDT) + l32;
        uint4 r;
        if (FUSE) {
            uint4 sv = *((const uint4*)(sub + (size_t)d * LDT) + l32);
            r.x = pack2(2.0f * acc[0] - bf2f((ushort)sv.x),
                        2.0f * acc[1] - bf2f((ushort)(sv.x >> 16)));
            r.y = pack2(2.0f * acc[2] - bf2f((ushort)sv.y),
                        2.0f * acc[3] - bf2f((ushort)(sv.y >> 16)));
            r.z = pack2(2.0f * acc[4] - bf2f((ushort)sv.z),
                        2.0f * acc[5] - bf2f((ushort)(sv.z >> 16)));
            r.w = pack2(2.0f * acc[6] - bf2f((ushort)sv.w),
                        2.0f * acc[7] - bf2f((ushort)(sv.w >> 16)));
        } else {
            r.x = pack2(acc[0], acc[1]);
            r.y = pack2(acc[2], acc[3]);
            r.z = pack2(acc[4], acc[5]);
            r.w = pack2(acc[6], acc[7]);
        }
        *op = r;
    }
}

// ---------------- MFMA matmul: 128 rows x FULL 256 cols per block -----------
template <int K>
__global__ __launch_bounds__(512, 4) void k_mm7(
    const ushort* __restrict__ A, int lda,
    int m0, int m1, int m2, int m3, int m4,
    const ushort* __restrict__ Wt, const float* __restrict__ bias,
    ushort* __restrict__ H, int ldh, int M) {
    constexpr int NT = K / 32;
    __shared__ ushort As[3][128 * 32];
    __shared__ ushort Bs[3][256 * 32];
    int tid = threadIdx.x;
    int lane = tid & 63, w = tid >> 6;
    int wm = w >> 2, wn = w & 3;
    int rowBase = blockIdx.x * 128;
    int srow = lane >> 2;
    int c16 = lane & 3;

    f32x4 acc[4][4];
#pragma unroll
    for (int i = 0; i < 4; ++i)
#pragma unroll
        for (int j = 0; j < 4; ++j) acc[i][j] = (f32x4){0.f, 0.f, 0.f, 0.f};

    auto stage = [&](int t) {
        int kk = t * 32;
        int slot = kk >> 8;
        int coff = (slot == 0 ? m0 : slot == 1 ? m1 : slot == 2 ? m2
                    : slot == 3 ? m3 : m4) + (kk & 255);
        int b = t % 3;
        {
            int r = w * 16 + srow;
            int cs = c16 ^ ((r >> 1) & 3);
            int grow = rowBase + r;
            if (grow > M - 1) grow = M - 1;
            const ushort* gp = A + (size_t)grow * lda + coff + cs * 8;
            __builtin_amdgcn_global_load_lds(
                (const __attribute__((address_space(1))) void*)gp,
                (__attribute__((address_space(3))) void*)((char*)&As[b][0] + w * 1024),
                16, 0, 0);
        }
#pragma unroll
        for (int q = 0; q < 2; ++q) {
            int seg = w * 2 + q;
            int r = seg * 16 + srow;
            int cs = c16 ^ ((r >> 1) & 3);
            const ushort* gp = Wt + (size_t)r * K + kk + cs * 8;
            __builtin_amdgcn_global_load_lds(
                (const __attribute__((address_space(1))) void*)gp,
                (__attribute__((address_space(3))) void*)((char*)&Bs[b][0] + seg * 1024),
                16, 0, 0);
        }
    };

    stage(0);
    stage(1);

    for (int t = 0; t < NT; ++t) {
        if (t + 1 < NT) {
            asm volatile("s_waitcnt vmcnt(3)" ::: "memory");
        } else {
            asm volatile("s_waitcnt vmcnt(0)" ::: "memory");
        }
        __builtin_amdgcn_s_barrier();
        if (t + 2 < NT) stage(t + 2);

        int b = t % 3;
        short8 af[4], bf[4];
#pragma unroll
        for (int mi = 0; mi < 4; ++mi) {
            int r = wm * 64 + mi * 16 + (lane & 15);
            int j = (lane >> 4) ^ ((r >> 1) & 3);
            af[mi] = *(const short8*)((const char*)&As[b][0] + r * 64 + j * 16);
        }
#pragma unroll
        for (int ni = 0; ni < 4; ++ni) {
            int r = wn * 64 + ni * 16 + (lane & 15);
            int j = (lane >> 4) ^ ((r >> 1) & 3);
            bf[ni] = *(const short8*)((const char*)&Bs[b][0] + r * 64 + j * 16);
        }
#pragma unroll
        for (int mi = 0; mi < 4; ++mi)
#pragma unroll
            for (int ni = 0; ni < 4; ++ni)
                acc[mi][ni] = __builtin_amdgcn_mfma_f32_16x16x32_bf16(
                    af[mi], bf[ni], acc[mi][ni], 0, 0, 0);
    }

    int lg = lane >> 4;
    float bv[4];
#pragma unroll
    for (int ni = 0; ni < 4; ++ni)
        bv[ni] = bias[wn * 64 + ni * 16 + (lane & 15)];
#pragma unroll
    for (int mi = 0; mi < 4; ++mi) {
#pragma unroll
        for (int r = 0; r < 4; ++r) {
            int row = rowBase + wm * 64 + mi * 16 + lg * 4 + r;
            if (row >= M) continue;
#pragma unroll
            for (int ni = 0; ni < 4; ++ni) {
                int colL = wn * 64 + ni * 16 + (lane & 15);
                float v = acc[mi][ni][r] + bv[ni];
                v = fmaxf(v, 0.0f);
                H[(size_t)row * ldh + colL] = f2bf(v);
            }
        }
    }
}

// ---------------- pooling (bf16 input, compact stride) ----------------

__global__ void k_pool(const ushort* __restrict__ h, const int* __restrict__ batch,
                       float* __restrict__ sums, float* __restrict__ cnts) {
    int f = threadIdx.x;
    int n0 = blockIdx.x * 128;
    if (n0 >= NN) return;
    int nEnd = n0 + 128 < NN ? n0 + 128 : NN;
    int cur = batch[n0];
    float acc = 0.0f, c = 0.0f;
    for (int n = n0; n < nEnd; ++n) {
        int b = batch[n];
        if (b != cur) {
            atomicAdd(&sums[cur * HID + f], acc);
            if (f == 0) atomicAdd(&cnts[cur], c);
            acc = 0.0f; c = 0.0f; cur = b;
        }
        acc += bf2f(h[(size_t)n * HID + f]);
        c += 1.0f;
    }
    atomicAdd(&sums[cur * HID + f], acc);
    if (f == 0) atomicAdd(&cnts[cur], c);
}

__global__ void k_gdiv(const float* __restrict__ sums, const float* __restrict__ cnts,
                       float* __restrict__ g) {
    int i = blockIdx.x * 256 + threadIdx.x;
    int b = i >> 8;
    g[i] = sums[i] / fmaxf(cnts[b], 1.0f);
}

// ---------------- MLP (fp32, tiny) ----------------

template <int RELU>
__global__ void k_fc(const float* __restrict__ in, const float* __restrict__ W,
                     const float* __restrict__ bias, float* __restrict__ out,
                     int K, int Nc) {
    __shared__ float s[512];
    int gi = blockIdx.x;
    for (int i = threadIdx.x; i < K; i += blockDim.x) s[i] = in[gi * K + i];
    __syncthreads();
    int c = blockIdx.y * blockDim.x + threadIdx.x;
    if (c < Nc) {
        float acc = bias[c];
        for (int k = 0; k < K; ++k) acc += s[k] * W[k * Nc + c];
        out[gi * Nc + c] = RELU ? fmaxf(acc, 0.0f) : acc;
    }
}

__global__ void k_fc3_lsm(const float* __restrict__ in, const float* __restrict__ W,
                          const float* __restrict__ b, float* __restrict__ out) {
    __shared__ float s[HID];
    __shared__ float lg[NCLS];
    int gi = blockIdx.x;
    s[threadIdx.x] = in[gi * HID + threadIdx.x];
    __syncthreads();
    if (threadIdx.x < NCLS) {
        float acc = b[threadIdx.x];
        for (int k = 0; k < HID; ++k) acc += s[k] * W[k * NCLS + threadIdx.x];
        lg[threadIdx.x] = acc;
    }
    __syncthreads();
    if (threadIdx.x < NCLS) {
        float m = -1e30f;
        for (int c = 0; c < NCLS; ++c) m = fmaxf(m, lg[c]);
        float sum = 0.0f;
        for (int c = 0; c < NCLS; ++c) sum += expf(lg[c] - m);
        out[gi * NCLS + threadIdx.x] = lg[threadIdx.x] - m - logf(sum);
    }
}

// ---------------- launch ----------------

extern "C" void kernel_launch(void* const* d_in, const int* in_sizes, int n_in,
                              void* d_out, int out_size, void* d_ws, size_t ws_size,
                              hipStream_t stream) {
    const float* x = (const float*)d_in[0];
    const int* ei = (const int*)d_in[1];
    const int* src = ei;
    const int* dst = ei + NE;
    const int* batch = (const int*)d_in[2];
    const float* W1 = (const float*)d_in[3];
    const float* b1 = (const float*)d_in[4];
    const float* W2 = (const float*)d_in[5];
    const float* b2 = (const float*)d_in[6];
    const float* W3 = (const float*)d_in[7];
    const float* b3 = (const float*)d_in[8];
    const float* fc1w = (const float*)d_in[9];
    const float* fc1b = (const float*)d_in[10];
    const float* fc2w = (const float*)d_in[11];
    const float* fc2b = (const float*)d_in[12];
    const float* fc3w = (const float*)d_in[13];
    const float* fc3b = (const float*)d_in[14];
    float* out = (float*)d_out;

    char* p = (char*)d_ws;
    auto carve = [&](size_t bytes) {
        char* r = p;
        p += align_up(bytes, 256);
        return (void*)r;
    };
    ushort* Tbig = (ushort*)carve((size_t)NN * LDT * 2);
    ushort* hA = (ushort*)carve((size_t)NN * HID * 2);
    ushort* Wt1 = (ushort*)carve((size_t)HID * 384 * 2);
    ushort* Wt2 = (ushort*)carve((size_t)HID * 1024 * 2);
    ushort* Wt3 = (ushort*)carve((size_t)HID * 1280 * 2);
    int* ideg = (int*)carve((size_t)NN * 4);
    float* dis = (float*)carve((size_t)NN * 4);
    uint2* em = (uint2*)carve((size_t)NE * 8);
    uint* cellcnt32 = (uint*)carve((size_t)NCELL * 2);
    int* cellptr = (int*)carve((size_t)(NCELL + 1) * 4);
    ushort* rank16 = (ushort*)carve((size_t)NE * 2);
    int* rpn = (int*)carve((size_t)(NN + 1) * 4);
    int* bsum = (int*)carve((size_t)NSCB * 4);
    float* psum = (float*)carve((size_t)NG * HID * 4);
    float* pcnt = (float*)carve((size_t)NG * 4);
    float* g = (float*)carve((size_t)NG * HID * 4);
    float* f1 = (float*)carve((size_t)NG * 512 * 4);
    float* f2 = (float*)carve((size_t)NG * HID * 4);

    hipMemsetAsync(ideg, 0, (size_t)NN * 4, stream);
    hipMemsetAsync(cellcnt32, 0, (size_t)NCELL * 2, stream);
    hipMemsetAsync(psum, 0, (size_t)NG * HID * 4, stream);
    hipMemsetAsync(pcnt, 0, (size_t)NG * 4, stream);

    // counting sort of edges into (dst, src-chunk) cells; ranks stored inline
    k_degcnt<<<(NE + 255) / 256, 256, 0, stream>>>(src, dst, ideg, cellcnt32, rank16);
    k_scanA_dis<<<NSCB + NDISB, 256, 0, stream>>>(cellcnt32, cellptr, bsum, ideg, dis);
    k_scanB<<<1, 1024, 0, stream>>>(bsum, NSCB);
    k_scanC<<<NSCB, 256, 0, stream>>>(bsum, cellptr, rpn);
    // fused: atomic-free fill + weight transpose + x spread
    k_fused_prep<<<FB + WTB + SXB, 256, 0, stream>>>(
        src, dst, dis, cellptr, rank16, em,
        W1, W2, W3, Wt1, Wt2, Wt3, x, Tbig);

    int mmg = (NN + 127) / 128;   // 391 blocks, full 256-col tiles

    // ---- layer 1: x@0 (128w), T1@128, T2@256; mm K=384 -> h1 @ col 1024 ----
    k_prop128<0><<<NN / 8, 512, 0, stream>>>(rpn, em, Tbig + 0, nullptr, Tbig + 128);
    k_prop128<1><<<NN / 8, 512, 0, stream>>>(rpn, em, Tbig + 128, Tbig + 0, Tbig + 256);
    k_mm7<384><<<mmg, 512, 0, stream>>>(Tbig, LDT, 0, 256, 0, 0, 0,
                                        Wt1, b1, Tbig + 1024, LDT, NN);

    // ---- layer 2: T0@1024, T1@0, T2@256, T3@512; mm K=1024 -> h2 @ col 768 ----
    k_prop256<0><<<NN / 8, 512, 0, stream>>>(rpn, em, Tbig + 1024, nullptr, Tbig + 0);
    k_prop256<1><<<NN / 8, 512, 0, stream>>>(rpn, em, Tbig + 0, Tbig + 1024, Tbig + 256);
    k_prop256<1><<<NN / 8, 512, 0, stream>>>(rpn, em, Tbig + 256, Tbig + 0, Tbig + 512);
    k_mm7<1024><<<mmg, 512, 0, stream>>>(Tbig, LDT, 1024, 0, 256, 512, 0,
                                         Wt2, b2, Tbig + 768, LDT, NN);

    // ---- layer 3: T0@768, T1@1024, T2@0, T3@256, T4@512; mm K=1280 -> hA ----
    k_prop256<0><<<NN / 8, 512, 0, stream>>>(rpn, em, Tbig + 768, nullptr, Tbig + 1024);
    k_prop256<1><<<NN / 8, 512, 0, stream>>>(rpn, em, Tbig + 1024, Tbig + 768, Tbig + 0);
    k_prop256<1><<<NN / 8, 512, 0, stream>>>(rpn, em, Tbig + 0, Tbig + 1024, Tbig + 256);
    k_prop256<1><<<NN / 8, 512, 0, stream>>>(rpn, em, Tbig + 256, Tbig + 0, Tbig + 512);
    k_mm7<1280><<<mmg, 512, 0, stream>>>(Tbig, LDT, 768, 1024, 0, 256, 512,
                                         Wt3, b3, hA, HID, NN);

    // ---- pool + MLP ----
    k_pool<<<(NN + 127) / 128, 256, 0, stream>>>(hA, batch, psum, pcnt);
    k_gdiv<<<(NG * HID) / 256, 256, 0, stream>>>(psum, pcnt, g);
    k_fc<1><<<dim3(NG, 2), 256, 0, stream>>>(g, fc1w, fc1b, f1, HID, 512);
    k_fc<1><<<dim3(NG, 1), 256, 0, stream>>>(f1, fc2w, fc2b, f2, 512, HID);
    k_fc3_lsm<<<NG, 256, 0, stream>>>(f2, fc3w, fc3b, out);
}

// Round 12
// 781.663 us; speedup vs baseline: 1.1919x; 1.1919x over previous
//
#include <hip/hip_runtime.h>
#include <cstdint>
#include <cstddef>

#define NN 50000
#define NE 800000
#define FIN 128
#define HID 256
#define NCLS 10
#define NG 64
#define LDT 1280        // Tbig row stride in elements (5 * 256)

// counting-sort geometry: key = dst*NCH + (src>>12); chunk = 4096 src rows
#define NCH 13
#define NCELL (NN * NCH)              // 650,000 (even)
#define NSCB ((NCELL + 255) / 256)    // 2540 scan blocks
#define NDISB ((NN + 255) / 256)      // 196 blocks for dis

// fused preproc kernel block ranges
#define FB 3125                        // fill blocks
#define WTB 2688                       // wtall blocks (384+1024+1280)
#define SXB 12500                      // spread_x blocks

typedef unsigned int uint;
typedef unsigned short ushort;
typedef __attribute__((ext_vector_type(8))) short short8;
typedef __attribute__((ext_vector_type(4))) float f32x4;

static inline size_t align_up(size_t v, size_t a) { return (v + a - 1) / a * a; }

__device__ __forceinline__ float bf2f(ushort u) {
    union { uint i; float f; } v; v.i = (uint)u << 16; return v.f;
}
__device__ __forceinline__ ushort f2bf(float f) {
    union { uint i; float f; } v; v.f = f;
    uint i = v.i;
    uint r = (i + 0x7fffu + ((i >> 16) & 1u)) >> 16;
    return (ushort)r;
}
__device__ __forceinline__ uint pack2(float a, float b) {
    return (uint)f2bf(a) | ((uint)f2bf(b) << 16);
}

// ---------------- graph preprocessing ----------------
// cellcnt packed 2 cells/u32; atomic old value = edge's rank within cell.

__global__ void k_degcnt(const int* __restrict__ src, const int* __restrict__ dst,
                         int* __restrict__ ideg, uint* __restrict__ cellcnt32,
                         ushort* __restrict__ rank16) {
    int e = blockIdx.x * 256 + threadIdx.x;
    if (e < NE) {
        int s = src[e], d = dst[e];
        atomicAdd(&ideg[s], 1);
        int cell = d * NCH + (s >> 12);
        uint old = atomicAdd(&cellcnt32[cell >> 1], 1u << ((cell & 1) * 16));
        rank16[e] = (ushort)((old >> ((cell & 1) * 16)) & 0xffffu);
    }
}

// scanA over NCELL packed counts; extra blocks compute dis from ideg
__global__ void k_scanA_dis(const uint* __restrict__ cnt32, int* __restrict__ rp,
                            int* __restrict__ bsum, const int* __restrict__ ideg,
                            float* __restrict__ dis) {
    if (blockIdx.x >= NSCB) {
        int n = (blockIdx.x - NSCB) * 256 + threadIdx.x;
        if (n < NN) {
            int d = ideg[n];
            dis[n] = (d > 0) ? rsqrtf((float)d) : 0.0f;
        }
        return;
    }
    __shared__ int s[256];
    int i = blockIdx.x * 256 + threadIdx.x;
    int v = 0;
    if (i < NCELL) v = (int)((cnt32[i >> 1] >> ((i & 1) * 16)) & 0xffffu);
    s[threadIdx.x] = v;
    __syncthreads();
    for (int off = 1; off < 256; off <<= 1) {
        int t = (threadIdx.x >= (unsigned)off) ? s[threadIdx.x - off] : 0;
        __syncthreads();
        s[threadIdx.x] += t;
        __syncthreads();
    }
    if (i < NCELL) rp[i] = s[threadIdx.x] - v;
    if (threadIdx.x == 255) bsum[blockIdx.x] = s[255];
}

// in-place exclusive scan, single block of 1024, multi-pass
__global__ void k_scanB(int* __restrict__ b, int n) {
    __shared__ int s[1024];
    __shared__ int carry;
    if (threadIdx.x == 0) carry = 0;
    __syncthreads();
    for (int base = 0; base < n; base += 1024) {
        int i = base + threadIdx.x;
        int v = (i < n) ? b[i] : 0;
        s[threadIdx.x] = v;
        __syncthreads();
        for (int off = 1; off < 1024; off <<= 1) {
            int t = (threadIdx.x >= (unsigned)off) ? s[threadIdx.x - off] : 0;
            __syncthreads();
            s[threadIdx.x] += t;
            __syncthreads();
        }
        int c = carry;
        if (i < n) b[i] = c + s[threadIdx.x] - v;
        __syncthreads();
        if (threadIdx.x == 0) carry = c + s[1023];
        __syncthreads();
    }
}

__global__ void k_scanC(const int* __restrict__ bsum, int* __restrict__ rp,
                        int* __restrict__ rpn) {
    int i = blockIdx.x * 256 + threadIdx.x;
    if (i < NCELL) {
        int v = rp[i] + bsum[blockIdx.x];
        rp[i] = v;
        if (i % NCH == 0) rpn[i / NCH] = v;   // node-level row ptr
    }
    if (i == 0) rpn[NN] = NE;
}

// ---------------- fused: fill (atomic-free) + weight transpose + spread_x ---
__global__ void k_fused_prep(
    const int* __restrict__ src, const int* __restrict__ dst,
    const float* __restrict__ dis, const int* __restrict__ cellptr,
    const ushort* __restrict__ rank16, uint2* __restrict__ em,
    const float* __restrict__ W1, const float* __restrict__ W2,
    const float* __restrict__ W3, ushort* __restrict__ Wt1,
    ushort* __restrict__ Wt2, ushort* __restrict__ Wt3,
    const float* __restrict__ x, ushort* __restrict__ T) {
    int b = blockIdx.x;
    if (b < FB) {
        int e = b * 256 + threadIdx.x;
        if (e < NE) {
            int s = src[e], d = dst[e];
            int cell = d * NCH + (s >> 12);
            int pos = cellptr[cell] + (int)rank16[e];
            uint2 m;
            m.x = (uint)s;
            m.y = __float_as_uint(-dis[s] * dis[d]);
            em[pos] = m;
        }
        return;
    }
    if (b < FB + WTB) {
        int i = (b - FB) * 256 + threadIdx.x;
        if (i < 384 * 256) {
            int k = i >> 8, n = i & 255;
            Wt1[(size_t)n * 384 + k] = f2bf(W1[i]);
            return;
        }
        i -= 384 * 256;
        if (i < 1024 * 256) {
            int k = i >> 8, n = i & 255;
            Wt2[(size_t)n * 1024 + k] = f2bf(W2[i]);
            return;
        }
        i -= 1024 * 256;
        if (i < 1280 * 256) {
            int k = i >> 8, n = i & 255;
            Wt3[(size_t)n * 1280 + k] = f2bf(W3[i]);
        }
        return;
    }
    int i = (b - FB - WTB) * 256 + threadIdx.x;
    if (i < NN * 64) {
        int m = i >> 6, p = i & 63;
        const float* xp = x + (size_t)m * FIN + p * 2;
        uint* tp = (uint*)(T + (size_t)m * LDT) + p;
        *tp = pack2(xp[0], xp[1]);
    }
}

// ---------------- prop: wave-per-node, chunk-sorted edges (r10 form) --------
// wave-uniform scalars via readfirstlane; 8B/lane gathers; 8-deep em batches.
template <int FUSE, int F>
__global__ __launch_bounds__(512) void k_prop3(
    const int* __restrict__ rpn, const uint2* __restrict__ em,
    const ushort* __restrict__ h, const ushort* __restrict__ sub,
    ushort* __restrict__ out) {
    constexpr int NV = (F == 256) ? 4 : 2;
    int wv = __builtin_amdgcn_readfirstlane(threadIdx.x >> 6);
    int d = blockIdx.x * 8 + wv;
    int lane = threadIdx.x & 63;
    int beg = rpn[d], end = rpn[d + 1];
    float a[NV];
#pragma unroll
    for (int j = 0; j < NV; ++j) a[j] = 0.0f;

    int e = beg;
    int nfull = (end - beg) >> 3;
    if (nfull > 0) {
        uint2 mt[8];
#pragma unroll
        for (int u = 0; u < 8; ++u) mt[u] = em[e + u];
        for (int g = 0; g < nfull; ++g) {
            uint2 mtn[8];
            if (F == 256) {
                uint2 gg[8];
#pragma unroll
                for (int u = 0; u < 8; ++u)
                    gg[u] = *((const uint2*)(h + (size_t)mt[u].x * LDT) + lane);
#pragma unroll
                for (int u = 0; u < 8; ++u) {
                    int pe = e + 8 + u; if (pe > end - 1) pe = end - 1;
                    mtn[u] = em[pe];
                }
#pragma unroll
                for (int u = 0; u < 8; ++u) {
                    float wvv = __uint_as_float(mt[u].y);
                    a[0] += wvv * bf2f((ushort)gg[u].x);
                    a[1] += wvv * bf2f((ushort)(gg[u].x >> 16));
                    a[2] += wvv * bf2f((ushort)gg[u].y);
                    a[3] += wvv * bf2f((ushort)(gg[u].y >> 16));
                }
            } else {
                uint gg[8];
#pragma unroll
                for (int u = 0; u < 8; ++u)
                    gg[u] = *((const uint*)(h + (size_t)mt[u].x * LDT) + lane);
#pragma unroll
                for (int u = 0; u < 8; ++u) {
                    int pe = e + 8 + u; if (pe > end - 1) pe = end - 1;
                    mtn[u] = em[pe];
                }
#pragma unroll
                for (int u = 0; u < 8; ++u) {
                    float wvv = __uint_as_float(mt[u].y);
                    a[0] += wvv * bf2f((ushort)gg[u]);
                    a[1] += wvv * bf2f((ushort)(gg[u] >> 16));
                }
            }
#pragma unroll
            for (int u = 0; u < 8; ++u) mt[u] = mtn[u];
            e += 8;
        }
    }
    for (; e + 4 <= end; e += 4) {
        uint2 mt[4];
#pragma unroll
        for (int u = 0; u < 4; ++u) mt[u] = em[e + u];
        if (F == 256) {
            uint2 gg[4];
#pragma unroll
            for (int u = 0; u < 4; ++u)
                gg[u] = *((const uint2*)(h + (size_t)mt[u].x * LDT) + lane);
#pragma unroll
            for (int u = 0; u < 4; ++u) {
                float wvv = __uint_as_float(mt[u].y);
                a[0] += wvv * bf2f((ushort)gg[u].x);
                a[1] += wvv * bf2f((ushort)(gg[u].x >> 16));
                a[2] += wvv * bf2f((ushort)gg[u].y);
                a[3] += wvv * bf2f((ushort)(gg[u].y >> 16));
            }
        } else {
            uint gg[4];
#pragma unroll
            for (int u = 0; u < 4; ++u)
                gg[u] = *((const uint*)(h + (size_t)mt[u].x * LDT) + lane);
#pragma unroll
            for (int u = 0; u < 4; ++u) {
                float wvv = __uint_as_float(mt[u].y);
                a[0] += wvv * bf2f((ushort)gg[u]);
                a[1] += wvv * bf2f((ushort)(gg[u] >> 16));
            }
        }
    }
    for (; e < end; ++e) {
        uint2 m0 = em[e];
        float w0 = __uint_as_float(m0.y);
        if (F == 256) {
            uint2 g0 = *((const uint2*)(h + (size_t)m0.x * LDT) + lane);
            a[0] += w0 * bf2f((ushort)g0.x); a[1] += w0 * bf2f((ushort)(g0.x >> 16));
            a[2] += w0 * bf2f((ushort)g0.y); a[3] += w0 * bf2f((ushort)(g0.y >> 16));
        } else {
            uint g0 = *((const uint*)(h + (size_t)m0.x * LDT) + lane);
            a[0] += w0 * bf2f((ushort)g0); a[1] += w0 * bf2f((ushort)(g0 >> 16));
        }
    }

    if (F == 256) {
        uint2* op = (uint2*)(out + (size_t)d * LDT) + lane;
        if (FUSE) {
            uint2 sv = *((const uint2*)(sub + (size_t)d * LDT) + lane);
            uint2 r;
            r.x = pack2(2.0f * a[0] - bf2f((ushort)sv.x),
                        2.0f * a[1] - bf2f((ushort)(sv.x >> 16)));
            r.y = pack2(2.0f * a[2] - bf2f((ushort)sv.y),
                        2.0f * a[3] - bf2f((ushort)(sv.y >> 16)));
            *op = r;
        } else {
            uint2 r;
            r.x = pack2(a[0], a[1]);
            r.y = pack2(a[2], a[3]);
            *op = r;
        }
    } else {
        uint* op = (uint*)(out + (size_t)d * LDT) + lane;
        if (FUSE) {
            uint sv = *((const uint*)(sub + (size_t)d * LDT) + lane);
            *op = pack2(2.0f * a[0] - bf2f((ushort)sv),
                        2.0f * a[1] - bf2f((ushort)(sv >> 16)));
        } else {
            *op = pack2(a[0], a[1]);
        }
    }
}

// ---------------- MFMA matmul: 128 rows x FULL 256 cols per block -----------
template <int K>
__global__ __launch_bounds__(512, 4) void k_mm7(
    const ushort* __restrict__ A, int lda,
    int m0, int m1, int m2, int m3, int m4,
    const ushort* __restrict__ Wt, const float* __restrict__ bias,
    ushort* __restrict__ H, int ldh, int M) {
    constexpr int NT = K / 32;
    __shared__ ushort As[3][128 * 32];
    __shared__ ushort Bs[3][256 * 32];
    int tid = threadIdx.x;
    int lane = tid & 63, w = tid >> 6;
    int wm = w >> 2, wn = w & 3;
    int rowBase = blockIdx.x * 128;
    int srow = lane >> 2;
    int c16 = lane & 3;

    f32x4 acc[4][4];
#pragma unroll
    for (int i = 0; i < 4; ++i)
#pragma unroll
        for (int j = 0; j < 4; ++j) acc[i][j] = (f32x4){0.f, 0.f, 0.f, 0.f};

    auto stage = [&](int t) {
        int kk = t * 32;
        int slot = kk >> 8;
        int coff = (slot == 0 ? m0 : slot == 1 ? m1 : slot == 2 ? m2
                    : slot == 3 ? m3 : m4) + (kk & 255);
        int b = t % 3;
        {
            int r = w * 16 + srow;
            int cs = c16 ^ ((r >> 1) & 3);
            int grow = rowBase + r;
            if (grow > M - 1) grow = M - 1;
            const ushort* gp = A + (size_t)grow * lda + coff + cs * 8;
            __builtin_amdgcn_global_load_lds(
                (const __attribute__((address_space(1))) void*)gp,
                (__attribute__((address_space(3))) void*)((char*)&As[b][0] + w * 1024),
                16, 0, 0);
        }
#pragma unroll
        for (int q = 0; q < 2; ++q) {
            int seg = w * 2 + q;
            int r = seg * 16 + srow;
            int cs = c16 ^ ((r >> 1) & 3);
            const ushort* gp = Wt + (size_t)r * K + kk + cs * 8;
            __builtin_amdgcn_global_load_lds(
                (const __attribute__((address_space(1))) void*)gp,
                (__attribute__((address_space(3))) void*)((char*)&Bs[b][0] + seg * 1024),
                16, 0, 0);
        }
    };

    stage(0);
    stage(1);

    for (int t = 0; t < NT; ++t) {
        if (t + 1 < NT) {
            asm volatile("s_waitcnt vmcnt(3)" ::: "memory");
        } else {
            asm volatile("s_waitcnt vmcnt(0)" ::: "memory");
        }
        __builtin_amdgcn_s_barrier();
        if (t + 2 < NT) stage(t + 2);

        int b = t % 3;
        short8 af[4], bf[4];
#pragma unroll
        for (int mi = 0; mi < 4; ++mi) {
            int r = wm * 64 + mi * 16 + (lane & 15);
            int j = (lane >> 4) ^ ((r >> 1) & 3);
            af[mi] = *(const short8*)((const char*)&As[b][0] + r * 64 + j * 16);
        }
#pragma unroll
        for (int ni = 0; ni < 4; ++ni) {
            int r = wn * 64 + ni * 16 + (lane & 15);
            int j = (lane >> 4) ^ ((r >> 1) & 3);
            bf[ni] = *(const short8*)((const char*)&Bs[b][0] + r * 64 + j * 16);
        }
#pragma unroll
        for (int mi = 0; mi < 4; ++mi)
#pragma unroll
            for (int ni = 0; ni < 4; ++ni)
                acc[mi][ni] = __builtin_amdgcn_mfma_f32_16x16x32_bf16(
                    af[mi], bf[ni], acc[mi][ni], 0, 0, 0);
    }

    int lg = lane >> 4;
    float bv[4];
#pragma unroll
    for (int ni = 0; ni < 4; ++ni)
        bv[ni] = bias[wn * 64 + ni * 16 + (lane & 15)];
#pragma unroll
    for (int mi = 0; mi < 4; ++mi) {
#pragma unroll
        for (int r = 0; r < 4; ++r) {
            int row = rowBase + wm * 64 + mi * 16 + lg * 4 + r;
            if (row >= M) continue;
#pragma unroll
            for (int ni = 0; ni < 4; ++ni) {
                int colL = wn * 64 + ni * 16 + (lane & 15);
                float v = acc[mi][ni][r] + bv[ni];
                v = fmaxf(v, 0.0f);
                H[(size_t)row * ldh + colL] = f2bf(v);
            }
        }
    }
}

// ---------------- pooling (bf16 input, compact stride) ----------------

__global__ void k_pool(const ushort* __restrict__ h, const int* __restrict__ batch,
                       float* __restrict__ sums, float* __restrict__ cnts) {
    int f = threadIdx.x;
    int n0 = blockIdx.x * 128;
    if (n0 >= NN) return;
    int nEnd = n0 + 128 < NN ? n0 + 128 : NN;
    int cur = batch[n0];
    float acc = 0.0f, c = 0.0f;
    for (int n = n0; n < nEnd; ++n) {
        int b = batch[n];
        if (b != cur) {
            atomicAdd(&sums[cur * HID + f], acc);
            if (f == 0) atomicAdd(&cnts[cur], c);
            acc = 0.0f; c = 0.0f; cur = b;
        }
        acc += bf2f(h[(size_t)n * HID + f]);
        c += 1.0f;
    }
    atomicAdd(&sums[cur * HID + f], acc);
    if (f == 0) atomicAdd(&cnts[cur], c);
}

__global__ void k_gdiv(const float* __restrict__ sums, const float* __restrict__ cnts,
                       float* __restrict__ g) {
    int i = blockIdx.x * 256 + threadIdx.x;
    int b = i >> 8;
    g[i] = sums[i] / fmaxf(cnts[b], 1.0f);
}

// ---------------- MLP (fp32, tiny) ----------------

template <int RELU>
__global__ void k_fc(const float* __restrict__ in, const float* __restrict__ W,
                     const float* __restrict__ bias, float* __restrict__ out,
                     int K, int Nc) {
    __shared__ float s[512];
    int gi = blockIdx.x;
    for (int i = threadIdx.x; i < K; i += blockDim.x) s[i] = in[gi * K + i];
    __syncthreads();
    int c = blockIdx.y * blockDim.x + threadIdx.x;
    if (c < Nc) {
        float acc = bias[c];
        for (int k = 0; k < K; ++k) acc += s[k] * W[k * Nc + c];
        out[gi * Nc + c] = RELU ? fmaxf(acc, 0.0f) : acc;
    }
}

__global__ void k_fc3_lsm(const float* __restrict__ in, const float* __restrict__ W,
                          const float* __restrict__ b, float* __restrict__ out) {
    __shared__ float s[HID];
    __shared__ float lg[NCLS];
    int gi = blockIdx.x;
    s[threadIdx.x] = in[gi * HID + threadIdx.x];
    __syncthreads();
    if (threadIdx.x < NCLS) {
        float acc = b[threadIdx.x];
        for (int k = 0; k < HID; ++k) acc += s[k] * W[k * NCLS + threadIdx.x];
        lg[threadIdx.x] = acc;
    }
    __syncthreads();
    if (threadIdx.x < NCLS) {
        float m = -1e30f;
        for (int c = 0; c < NCLS; ++c) m = fmaxf(m, lg[c]);
        float sum = 0.0f;
        for (int c = 0; c < NCLS; ++c) sum += expf(lg[c] - m);
        out[gi * NCLS + threadIdx.x] = lg[threadIdx.x] - m - logf(sum);
    }
}

// ---------------- launch ----------------

extern "C" void kernel_launch(void* const* d_in, const int* in_sizes, int n_in,
                              void* d_out, int out_size, void* d_ws, size_t ws_size,
                              hipStream_t stream) {
    const float* x = (const float*)d_in[0];
    const int* ei = (const int*)d_in[1];
    const int* src = ei;
    const int* dst = ei + NE;
    const int* batch = (const int*)d_in[2];
    const float* W1 = (const float*)d_in[3];
    const float* b1 = (const float*)d_in[4];
    const float* W2 = (const float*)d_in[5];
    const float* b2 = (const float*)d_in[6];
    const float* W3 = (const float*)d_in[7];
    const float* b3 = (const float*)d_in[8];
    const float* fc1w = (const float*)d_in[9];
    const float* fc1b = (const float*)d_in[10];
    const float* fc2w = (const float*)d_in[11];
    const float* fc2b = (const float*)d_in[12];
    const float* fc3w = (const float*)d_in[13];
    const float* fc3b = (const float*)d_in[14];
    float* out = (float*)d_out;

    char* p = (char*)d_ws;
    auto carve = [&](size_t bytes) {
        char* r = p;
        p += align_up(bytes, 256);
        return (void*)r;
    };
    ushort* Tbig = (ushort*)carve((size_t)NN * LDT * 2);
    ushort* hA = (ushort*)carve((size_t)NN * HID * 2);
    ushort* Wt1 = (ushort*)carve((size_t)HID * 384 * 2);
    ushort* Wt2 = (ushort*)carve((size_t)HID * 1024 * 2);
    ushort* Wt3 = (ushort*)carve((size_t)HID * 1280 * 2);
    int* ideg = (int*)carve((size_t)NN * 4);
    float* dis = (float*)carve((size_t)NN * 4);
    uint2* em = (uint2*)carve((size_t)NE * 8);
    uint* cellcnt32 = (uint*)carve((size_t)NCELL * 2);
    int* cellptr = (int*)carve((size_t)(NCELL + 1) * 4);
    ushort* rank16 = (ushort*)carve((size_t)NE * 2);
    int* rpn = (int*)carve((size_t)(NN + 1) * 4);
    int* bsum = (int*)carve((size_t)NSCB * 4);
    float* psum = (float*)carve((size_t)NG * HID * 4);
    float* pcnt = (float*)carve((size_t)NG * 4);
    float* g = (float*)carve((size_t)NG * HID * 4);
    float* f1 = (float*)carve((size_t)NG * 512 * 4);
    float* f2 = (float*)carve((size_t)NG * HID * 4);

    hipMemsetAsync(ideg, 0, (size_t)NN * 4, stream);
    hipMemsetAsync(cellcnt32, 0, (size_t)NCELL * 2, stream);
    hipMemsetAsync(psum, 0, (size_t)NG * HID * 4, stream);
    hipMemsetAsync(pcnt, 0, (size_t)NG * 4, stream);

    // counting sort of edges into (dst, src-chunk) cells; ranks stored inline
    k_degcnt<<<(NE + 255) / 256, 256, 0, stream>>>(src, dst, ideg, cellcnt32, rank16);
    k_scanA_dis<<<NSCB + NDISB, 256, 0, stream>>>(cellcnt32, cellptr, bsum, ideg, dis);
    k_scanB<<<1, 1024, 0, stream>>>(bsum, NSCB);
    k_scanC<<<NSCB, 256, 0, stream>>>(bsum, cellptr, rpn);
    // fused: atomic-free fill + weight transpose + x spread
    k_fused_prep<<<FB + WTB + SXB, 256, 0, stream>>>(
        src, dst, dis, cellptr, rank16, em,
        W1, W2, W3, Wt1, Wt2, Wt3, x, Tbig);

    int mmg = (NN + 127) / 128;   // 391 blocks, full 256-col tiles

    // ---- layer 1: x@0 (128w), T1@128, T2@256; mm K=384 -> h1 @ col 1024 ----
    k_prop3<0, 128><<<NN / 8, 512, 0, stream>>>(rpn, em, Tbig + 0, nullptr, Tbig + 128);
    k_prop3<1, 128><<<NN / 8, 512, 0, stream>>>(rpn, em, Tbig + 128, Tbig + 0, Tbig + 256);
    k_mm7<384><<<mmg, 512, 0, stream>>>(Tbig, LDT, 0, 256, 0, 0, 0,
                                        Wt1, b1, Tbig + 1024, LDT, NN);

    // ---- layer 2: T0@1024, T1@0, T2@256, T3@512; mm K=1024 -> h2 @ col 768 ----
    k_prop3<0, 256><<<NN / 8, 512, 0, stream>>>(rpn, em, Tbig + 1024, nullptr, Tbig + 0);
    k_prop3<1, 256><<<NN / 8, 512, 0, stream>>>(rpn, em, Tbig + 0, Tbig + 1024, Tbig + 256);
    k_prop3<1, 256><<<NN / 8, 512, 0, stream>>>(rpn, em, Tbig + 256, Tbig + 0, Tbig + 512);
    k_mm7<1024><<<mmg, 512, 0, stream>>>(Tbig, LDT, 1024, 0, 256, 512, 0,
                                         Wt2, b2, Tbig + 768, LDT, NN);

    // ---- layer 3: T0@768, T1@1024, T2@0, T3@256, T4@512; mm K=1280 -> hA ----
    k_prop3<0, 256><<<NN / 8, 512, 0, stream>>>(rpn, em, Tbig + 768, nullptr, Tbig + 1024);
    k_prop3<1, 256><<<NN / 8, 512, 0, stream>>>(rpn, em, Tbig + 1024, Tbig + 768, Tbig + 0);
    k_prop3<1, 256><<<NN / 8, 512, 0, stream>>>(rpn, em, Tbig + 0, Tbig + 1024, Tbig + 256);
    k_prop3<1, 256><<<NN / 8, 512, 0, stream>>>(rpn, em, Tbig + 256, Tbig + 0, Tbig + 512);
    k_mm7<1280><<<mmg, 512, 0, stream>>>(Tbig, LDT, 768, 1024, 0, 256, 512,
                                         Wt3, b3, hA, HID, NN);

    // ---- pool + MLP ----
    k_pool<<<(NN + 127) / 128, 256, 0, stream>>>(hA, batch, psum, pcnt);
    k_gdiv<<<(NG * HID) / 256, 256, 0, stream>>>(psum, pcnt, g);
    k_fc<1><<<dim3(NG, 2), 256, 0, stream>>>(g, fc1w, fc1b, f1, HID, 512);
    k_fc<1><<<dim3(NG, 1), 256, 0, stream>>>(f1, fc2w, fc2b, f2, 512, HID);
    k_fc3_lsm<<<NG, 256, 0, stream>>>(f2, fc3w, fc3b, out);
}